// Round 1
// 69.918 us; speedup vs baseline: 1.0168x; 1.0168x over previous
//
#include <hip/hip_runtime.h>

#define RS 66  // LDS row stride in floats (even -> 8B-aligned ds_read_b64)

typedef float v2f __attribute__((ext_vector_type(2)));

// Exponent-harvest accumulate: p is a product of <=16 pair-diffs.
// log2|prod| decomposes exactly as (biased-exponent sum, int) + log2(mantissa
// product). This replaces one quarter-rate v_log_f32 + v_max + v_add per group
// with 6 full-rate VALU ops (max/shr/iadd/and/or/fmul); the only v_log_f32
// left is ONE per thread at the very end.
// Clamp keeps duplicate-x rows finite (same semantics as previous kernel).
__device__ __forceinline__ void acc16(float p, int& ea, float& m) {
  p = __builtin_fmaxf(__builtin_fabsf(p), 1e-37f);  // >0, normal
  const int b = __float_as_int(p);   // sign clear -> b>>23 == biased exponent
  ea += (b >> 23);
  m *= __int_as_float((b & 0x007FFFFF) | 0x3F800000);  // mantissa in [1,2)
}

__device__ __forceinline__ void ld8v(const float* p, v2f (&r)[4]) {
#pragma unroll
  for (int k = 0; k < 4; ++k) r[k] = *reinterpret_cast<const v2f*>(p + 2 * k);
}

// 16 pairs: rows {a,b} of ei vs all 8 of ej.
// 8 v_pk_sub + 7 v_pk_mul + 1 mul + 6-op harvest = 22 instrs / 16 pairs
// (was 2x row8p = 22 instrs incl 2 logs = ~56 issue cycles; now ~44).
// Range: |e| <= e^5.2 ~ 181 -> 181^16 ~ 1e36 < f32 max, no overflow.
__device__ __forceinline__ void row16(float a, float b, const v2f (&ej)[4],
                                      int& ea, float& m) {
  v2f aa = {a, a}, bb = {b, b};
  v2f qa = ((aa - ej[0]) * (aa - ej[1])) * ((aa - ej[2]) * (aa - ej[3]));
  v2f qb = ((bb - ej[0]) * (bb - ej[1])) * ((bb - ej[2]) * (bb - ej[3]));
  v2f q = qa * qb;
  acc16(q.x * q.y, ea, m);
}

// all 64 cross pairs ei x ej -> 4 exponent harvests (alternating accumulators)
__device__ __forceinline__ void crossp(const v2f (&ei)[4], const v2f (&ej)[4],
                                       int& e0, float& m0, int& e1, float& m1) {
  row16(ei[0].x, ei[0].y, ej, e0, m0);
  row16(ei[1].x, ei[1].y, ej, e1, m1);
  row16(ei[2].x, ei[2].y, ej, e0, m0);
  row16(ei[3].x, ei[3].y, ej, e1, m1);
}

// all 28 pairs within one 8-chunk -> 2 groups of 14 (scalar; operand halves
// all distinct so packing gains nothing here)
__device__ __forceinline__ void diag(const v2f (&v)[4], int& e0, float& m0,
                                     int& e1, float& m1) {
  float a = v[0].x, b = v[0].y, c = v[1].x, d = v[1].y;
  float e = v[2].x, f = v[2].y, g = v[3].x, h = v[3].y;
  // group 1: ab ac ad ae af ag ah bc bd be bf bg bh cd  (14 pairs)
  float p1 = ((((a - b) * (a - c)) * ((a - d) * (a - e))) *
              (((a - f) * (a - g)) * ((a - h) * (b - c)))) *
             ((((b - d) * (b - e)) * ((b - f) * (b - g))) *
              ((b - h) * (c - d)));
  acc16(p1, e0, m0);
  // group 2: ce cf cg ch de df dg dh ef eg eh fg fh gh  (14 pairs)
  float p2 = ((((c - e) * (c - f)) * ((c - g) * (c - h))) *
              (((d - e) * (d - f)) * ((d - g) * (d - h)))) *
             ((((e - f) * (e - g)) * ((e - h) * (f - g))) *
              ((f - h) * (g - h)));
  acc16(p2, e1, m1);
}

// Block = 512 threads = 8 waves = 64 rows (lane = row in phase 2).
// Rotation schedule (no LUT): wave w owns chunk w; cross vs chunks w+1..w+3
// (mod 8) = 192 pairs, half of tile {w, w+4} = 32, diagonal chunk w = 28.
// Total 252/wave x 8 = 2016. 16 exponent harvests/thread -> bias 16*127.
__global__ __launch_bounds__(512, 8) void vander_kernel(
    const float* __restrict__ x, const float* __restrict__ alpha,
    const float* __restrict__ beta, float* __restrict__ out) {
  __shared__ float e_lds[64 * RS];
  __shared__ float xsum[64 * 9];
  __shared__ float ps[64 * 9];

  const int tid = threadIdx.x;
  const float c = -alpha[0] * 1.44269504088896340736f;  // -alpha * log2(e)

  // ---- phase 1: thread (r, cc) exps 8 values of row r into LDS ----
  {
    const int r = tid >> 3, cc = tid & 7;
    const float4* xp = reinterpret_cast<const float4*>(
        x + ((size_t)blockIdx.x * 64 + r) * 64 + cc * 8);
    float4 u = xp[0], v = xp[1];
    float* ew = &e_lds[r * RS + cc * 8];
    float2 t;
    t.x = __builtin_amdgcn_exp2f(c * u.x); t.y = __builtin_amdgcn_exp2f(c * u.y);
    *reinterpret_cast<float2*>(ew + 0) = t;
    t.x = __builtin_amdgcn_exp2f(c * u.z); t.y = __builtin_amdgcn_exp2f(c * u.w);
    *reinterpret_cast<float2*>(ew + 2) = t;
    t.x = __builtin_amdgcn_exp2f(c * v.x); t.y = __builtin_amdgcn_exp2f(c * v.y);
    *reinterpret_cast<float2*>(ew + 4) = t;
    t.x = __builtin_amdgcn_exp2f(c * v.z); t.y = __builtin_amdgcn_exp2f(c * v.w);
    *reinterpret_cast<float2*>(ew + 6) = t;
    xsum[r * 9 + cc] = ((u.x + u.y) + (u.z + u.w)) + ((v.x + v.y) + (v.z + v.w));
  }
  __syncthreads();

  // ---- phase 2: pair work, one small shared straight-line body ----
  const int lane = tid & 63;
  const int w = tid >> 6;  // 0..7, wave-uniform
  const float* myrow = &e_lds[lane * RS];

  v2f ei[4], ej[4];
  ld8v(myrow + w * 8, ei);
  int e0 = 0, e1 = 0;
  float m0 = 1.f, m1 = 1.f;  // 8 harvests each -> m < 2^8, exact

  ld8v(myrow + ((w + 1) & 7) * 8, ej);
  crossp(ei, ej, e0, m0, e1, m1);
  ld8v(myrow + ((w + 2) & 7) * 8, ej);
  crossp(ei, ej, e0, m0, e1, m1);
  ld8v(myrow + ((w + 3) & 7) * 8, ej);
  crossp(ei, ej, e0, m0, e1, m1);

  ld8v(myrow + ((w + 4) & 7) * 8, ej);
  if (w < 4) {  // tile {w, w+4}: rows 0-3 of chunk w vs chunk w+4
    row16(ei[0].x, ei[0].y, ej, e0, m0);
    row16(ei[1].x, ei[1].y, ej, e1, m1);
  } else {      // rows 4-7 of chunk w-4 (= ej) vs chunk w (= ei)
    row16(ej[2].x, ej[2].y, ei, e0, m0);
    row16(ej[3].x, ej[3].y, ei, e1, m1);
  }
  diag(ei, e0, m0, e1, m1);

  // log2|prod| = (sum of biased exps - 16*127) + log2(m0*m1), m0*m1 < 2^16
  float lv = (float)(e0 + e1 - 16 * 127) + __builtin_amdgcn_logf(m0 * m1);
  ps[lane * 9 + w] = lv;
  __syncthreads();

  // ---- phase 3: reduce + write (wave 0) ----
  if (w == 0) {
    const float* pp = &ps[lane * 9];
    const float* xq = &xsum[lane * 9];
    float lv2 = ((pp[0] + pp[1]) + (pp[2] + pp[3])) + ((pp[4] + pp[5]) + (pp[6] + pp[7]));
    float xs = ((xq[0] + xq[1]) + (xq[2] + xq[3])) + ((xq[4] + xq[5]) + (xq[6] + xq[7]));
    out[blockIdx.x * 64 + lane] =
        2.0f * (-beta[0] * xs + 0.69314718055994530942f * lv2);
  }
}

extern "C" void kernel_launch(void* const* d_in, const int* in_sizes, int n_in,
                              void* d_out, int out_size, void* d_ws, size_t ws_size,
                              hipStream_t stream) {
  const float* x = (const float*)d_in[0];
  const float* alpha = (const float*)d_in[1];
  const float* beta = (const float*)d_in[2];
  float* out = (float*)d_out;
  int nrows = in_sizes[0] / 64;  // 65536
  int grid = nrows / 64;         // 1024 blocks x 512 threads
  hipLaunchKernelGGL(vander_kernel, dim3(grid), dim3(512), 0, stream,
                     x, alpha, beta, out);
}